// Round 4
// baseline (153.659 us; speedup 1.0000x reference)
//
#include <hip/hip_runtime.h>

// cvmm: out[m] = x[m] @ w[sel[m]]
// x: [M,64] f32, sel: [M] i32, w: [8,64,64] f32, out: [M,64] f32
//
// R4: latency/MLP fix. R1-R3 were stall-bound (~2280 cyc per m-tile vs ~320
// issue cycles; all pipes <21% busy). Changes:
//  - depth-2 register pipeline: stage i+2's x/sel loads issue right after
//    stage i's f32->bf16 conversion (register WAR pins the order), so loads
//    are in flight ~2 iterations (~600+ cyc) before consumption.
//  - MT=16, grid=1024 (exactly 4 blocks/CU, one co-resident round).
//  - B fragments pinned in regs/AGPRs as R3 (asm barrier).
// Reg budget ~126: B 64 + stages 32 + af 8 + acc 8 + misc -> 4 waves/SIMD.

typedef __bf16 bf16x8 __attribute__((ext_vector_type(8)));
typedef float floatx4 __attribute__((ext_vector_type(4)));

#define MT 16  // m-tiles (16 rows each) per block

__global__ __launch_bounds__(256, 4) void cvmm_kernel(
    const float* __restrict__ x,
    const int* __restrict__ sel,
    const float* __restrict__ w,
    float* __restrict__ out,
    int M)
{
    const int lane = threadIdx.x & 63;
    const int wave = threadIdx.x >> 6;   // 0..3 -> n-tile
    const int n0   = wave << 4;          // n offset (16 cols per wave)
    const int quad = lane >> 4;          // 0..3
    const int l16  = lane & 15;

    // ---- Preload B fragments: B[k = quad*8+j][n = l16] per (expert, k-tile).
    floatx4 bfp[8][2];
#pragma unroll
    for (int e = 0; e < 8; ++e) {
#pragma unroll
        for (int t = 0; t < 2; ++t) {
            const float* wp = w + ((e * 64 + t * 32 + quad * 8) * 64) + (n0 + l16);
            bf16x8 f;
#pragma unroll
            for (int j = 0; j < 8; ++j) {
                f[j] = (__bf16)wp[j * 64];
            }
            bfp[e][t] = __builtin_bit_cast(floatx4, f);
        }
    }
    // Pin the fragments (prevent remat/sink into the loop).
#pragma unroll
    for (int e = 0; e < 8; ++e) {
#pragma unroll
        for (int t = 0; t < 2; ++t) {
            asm volatile("" : "+v"(bfp[e][t]));
        }
    }

    bf16x8 zf;
#pragma unroll
    for (int j = 0; j < 8; ++j) zf[j] = (__bf16)0.0f;

    const int mt0 = blockIdx.x * MT;
    const float* xbase  = x + (size_t)(mt0 << 4) * 64 + l16 * 64 + quad * 8;
    const int*  selbase = sel + (mt0 << 4) + l16;

#define LOAD_STAGE(i, La, Lb, Lc, Ld, S)                         \
    {                                                            \
        const float* xp = xbase + (size_t)(i) * 1024;            \
        La = *(const floatx4*)(xp);                              \
        Lb = *(const floatx4*)(xp + 4);                          \
        Lc = *(const floatx4*)(xp + 32);                         \
        Ld = *(const floatx4*)(xp + 36);                         \
        S  = selbase[(i) * 16];                                  \
    }

    // ---- Depth-2 pipeline prologue
    floatx4 A0, A1, A2, A3, B0, B1, B2, B3;
    int sA, sB;
    LOAD_STAGE(0, A0, A1, A2, A3, sA);
    LOAD_STAGE(1, B0, B1, B2, B3, sB);

#pragma unroll
    for (int i = 0; i < MT; ++i) {
        // ---- Convert current stage to bf16 A fragments (waits on its loads)
        floatx4 a0, a1, a2, a3;
        int s;
        if (i & 1) { a0 = B0; a1 = B1; a2 = B2; a3 = B3; s = sB; }
        else       { a0 = A0; a1 = A1; a2 = A2; a3 = A3; s = sA; }

        bf16x8 af0, af1;
#pragma unroll
        for (int j = 0; j < 4; ++j) {
            af0[j]     = (__bf16)a0[j];
            af0[j + 4] = (__bf16)a1[j];
            af1[j]     = (__bf16)a2[j];
            af1[j + 4] = (__bf16)a3[j];
        }

        // ---- Refill this stage with m-tile i+2 (issues now, consumed in 2 iters)
        if (i + 2 < MT) {
            if (i & 1) { LOAD_STAGE(i + 2, B0, B1, B2, B3, sB); }
            else       { LOAD_STAGE(i + 2, A0, A1, A2, A3, sA); }
        }

        // ---- Two independent masked MFMA chains (depth 8 each)
        floatx4 c0 = {0.0f, 0.0f, 0.0f, 0.0f};
        floatx4 c1 = {0.0f, 0.0f, 0.0f, 0.0f};
#pragma unroll
        for (int e = 0; e < 8; ++e) {
            const bool ok = (s == e);
            bf16x8 a0m = ok ? af0 : zf;
            bf16x8 a1m = ok ? af1 : zf;
            c0 = __builtin_amdgcn_mfma_f32_16x16x32_bf16(
                     a0m, __builtin_bit_cast(bf16x8, bfp[e][0]), c0, 0, 0, 0);
            c1 = __builtin_amdgcn_mfma_f32_16x16x32_bf16(
                     a1m, __builtin_bit_cast(bf16x8, bfp[e][1]), c1, 0, 0, 0);
        }

        // ---- Store: D[row = quad*4 + r][col = l16]
        const int m0 = (mt0 + i) << 4;
        float* op = out + (size_t)(m0 + quad * 4) * 64 + n0 + l16;
#pragma unroll
        for (int r = 0; r < 4; ++r) {
            op[(size_t)r * 64] = c0[r] + c1[r];
        }
    }
#undef LOAD_STAGE
}

extern "C" void kernel_launch(void* const* d_in, const int* in_sizes, int n_in,
                              void* d_out, int out_size, void* d_ws, size_t ws_size,
                              hipStream_t stream) {
    const float* x   = (const float*)d_in[0];
    const int*   sel = (const int*)d_in[1];
    const float* w   = (const float*)d_in[2];
    float*       out = (float*)d_out;

    const int M = in_sizes[0] / 64;                 // 262144
    const int mtiles = M / 16;                      // 16384
    const int blocks = (mtiles + MT - 1) / MT;      // 1024

    cvmm_kernel<<<blocks, 256, 0, stream>>>(x, sel, w, out, M);
}

// Round 5
// 126.059 us; speedup vs baseline: 1.2189x; 1.2189x over previous
//
#include <hip/hip_runtime.h>

// cvmm: out[m] = x[m] @ w[sel[m]]
// x: [M,64] f32, sel: [M] i32, w: [8,64,64] f32, out: [M,64] f32
//
// R5: structural rewrite of data movement. R1-R4 (direct per-wave fragment
// loads, any pipelining) all stall at ~60us / 1700 GB/s: scattered 32B-granule
// A-loads (2x line transactions, half-used lines), 4x re-read of x by the 4
// waves of a block, register-capped outstanding loads. Fix = canonical LDS
// staging:
//  - block streams contiguous 64-token chunks, lane-linear dwordx4 (perfectly
//    coalesced), cvt f32->bf16 once, ds_write with XOR-granule swizzle
//  - MFMA A-frags read from LDS as ds_read_b128 at the bank floor (swizzle:
//    8 slots x 8 lanes, all banks busy)
//  - double buffer, ONE barrier per chunk; next chunk's global loads issued
//    AFTER the barrier so the compiler's vmcnt(0)-before-s_barrier drain
//    cannot serialize the prefetch; loads in flight across full compute
//  - B fragments register-pinned per expert (as R3); masked-expert MFMA
// Grid: 1024 blocks x 4 chunks x 64 tokens = 262144. LDS 16 KB -> 4 blk/CU.

typedef __bf16 bf16x8 __attribute__((ext_vector_type(8)));
typedef __bf16 bf16x4 __attribute__((ext_vector_type(4)));
typedef float  floatx4 __attribute__((ext_vector_type(4)));

#define NCHUNK 4
#define CHUNK_LDS 8192   // 4 m-tiles * (16 rows * 128 B bf16)

__global__ __launch_bounds__(256, 4) void cvmm_kernel(
    const float* __restrict__ x,
    const int* __restrict__ sel,
    const float* __restrict__ w,
    float* __restrict__ out,
    int M)
{
    __shared__ __align__(16) unsigned char lds[2 * CHUNK_LDS];

    const int T    = threadIdx.x;
    const int lane = T & 63;
    const int wv   = T >> 6;     // 0..3 -> n-tile
    const int q    = lane >> 4;  // 0..3
    const int l16  = lane & 15;
    const int n0   = wv << 4;

    // ---- Preload B fragments: B[k = q*8+j][n = l16] per (expert, k-tile).
    floatx4 bfp[8][2];
#pragma unroll
    for (int e = 0; e < 8; ++e) {
#pragma unroll
        for (int t = 0; t < 2; ++t) {
            const float* wp = w + ((e * 64 + t * 32 + q * 8) * 64) + (n0 + l16);
            bf16x8 f;
#pragma unroll
            for (int j = 0; j < 8; ++j) f[j] = (__bf16)wp[j * 64];
            bfp[e][t] = __builtin_bit_cast(floatx4, f);
        }
    }
#pragma unroll
    for (int e = 0; e < 8; ++e)
#pragma unroll
        for (int t = 0; t < 2; ++t)
            asm volatile("" : "+v"(bfp[e][t]));

    bf16x8 zf;
#pragma unroll
    for (int j = 0; j < 8; ++j) zf[j] = (__bf16)0.0f;

    // ---- LDS addressing.
    // m-tile layout: 16 rows x 128 B (bf16), 16-B granules XOR-swizzled by row:
    //   phys(row, colbyte) = row*128 + (((colbyte>>4) ^ (row&7))<<4) + (colbyte&15)
    // Write (thread T, m-tile p): row = T>>4, colbyte = 8*(T&15)  [bf16x4]
    const int wrow  = T >> 4;
    const int wbase = wrow * 128 + (((((T & 15) >> 1)) ^ (wrow & 7)) << 4) + (T & 1) * 8;
    // Read (lane q,l16; frag t): row = l16, granule = q + 4t
    const int roff0 = l16 * 128 + (((q    ) ^ (l16 & 7)) << 4);
    const int roff1 = l16 * 128 + (((q + 4) ^ (l16 & 7)) << 4);

    const long tok0 = (long)blockIdx.x * (NCHUNK * 64);

    // ---- Prologue: load chunk 0 (registers) + its sel
    floatx4 R0, R1, R2, R3;
    int Sc0, Sc1, Sc2, Sc3, Sn0, Sn1, Sn2, Sn3;
    {
        const float* xc = x + tok0 * 64;
        R0 = *(const floatx4*)(xc + 0 * 1024 + 4 * T);
        R1 = *(const floatx4*)(xc + 1 * 1024 + 4 * T);
        R2 = *(const floatx4*)(xc + 2 * 1024 + 4 * T);
        R3 = *(const floatx4*)(xc + 3 * 1024 + 4 * T);
        const int* sp = sel + tok0 + l16;
        Sc0 = sp[0]; Sc1 = sp[16]; Sc2 = sp[32]; Sc3 = sp[48];
    }

    int buf = 0;
#pragma unroll
    for (int c = 0; c < NCHUNK; ++c) {
        // ---- Stage regs -> LDS (bf16, swizzled)
        unsigned char* lb = &lds[buf * CHUNK_LDS];
#define STAGE(p, Rv)                                                   \
        {                                                              \
            bf16x4 v;                                                  \
            v[0] = (__bf16)Rv[0]; v[1] = (__bf16)Rv[1];                \
            v[2] = (__bf16)Rv[2]; v[3] = (__bf16)Rv[3];                \
            *(bf16x4*)(lb + (p) * 2048 + wbase) = v;                   \
        }
        STAGE(0, R0) STAGE(1, R1) STAGE(2, R2) STAGE(3, R3)
#undef STAGE

        __syncthreads();   // staged data visible; drains before-barrier mem ops

        // ---- Prefetch next chunk AFTER the barrier (stays in flight
        //      across the whole compute phase below)
        if (c + 1 < NCHUNK) {
            const float* xc = x + (tok0 + (c + 1) * 64) * 64;
            R0 = *(const floatx4*)(xc + 0 * 1024 + 4 * T);
            R1 = *(const floatx4*)(xc + 1 * 1024 + 4 * T);
            R2 = *(const floatx4*)(xc + 2 * 1024 + 4 * T);
            R3 = *(const floatx4*)(xc + 3 * 1024 + 4 * T);
            const int* sp = sel + tok0 + (c + 1) * 64 + l16;
            Sn0 = sp[0]; Sn1 = sp[16]; Sn2 = sp[32]; Sn3 = sp[48];
        }

        // ---- Compute 4 m-tiles from LDS
#pragma unroll
        for (int i = 0; i < 4; ++i) {
            const bf16x8 af0 = *(const bf16x8*)(lb + i * 2048 + roff0);
            const bf16x8 af1 = *(const bf16x8*)(lb + i * 2048 + roff1);
            const int s = (i == 0) ? Sc0 : (i == 1) ? Sc1 : (i == 2) ? Sc2 : Sc3;

            floatx4 c0 = {0.0f, 0.0f, 0.0f, 0.0f};
            floatx4 c1 = {0.0f, 0.0f, 0.0f, 0.0f};
#pragma unroll
            for (int e = 0; e < 8; ++e) {
                const bool ok = (s == e);
                bf16x8 a0m = ok ? af0 : zf;
                bf16x8 a1m = ok ? af1 : zf;
                c0 = __builtin_amdgcn_mfma_f32_16x16x32_bf16(
                         a0m, __builtin_bit_cast(bf16x8, bfp[e][0]), c0, 0, 0, 0);
                c1 = __builtin_amdgcn_mfma_f32_16x16x32_bf16(
                         a1m, __builtin_bit_cast(bf16x8, bfp[e][1]), c1, 0, 0, 0);
            }

            // Store: D[row = q*4 + r][col = l16]
            const long m0 = tok0 + c * 64 + i * 16;
            float* op = out + (m0 + q * 4) * 64 + n0 + l16;
#pragma unroll
            for (int r = 0; r < 4; ++r) {
                op[(long)r * 64] = c0[r] + c1[r];
            }
        }

        Sc0 = Sn0; Sc1 = Sn1; Sc2 = Sn2; Sc3 = Sn3;
        buf ^= 1;
    }
}

extern "C" void kernel_launch(void* const* d_in, const int* in_sizes, int n_in,
                              void* d_out, int out_size, void* d_ws, size_t ws_size,
                              hipStream_t stream) {
    const float* x   = (const float*)d_in[0];
    const int*   sel = (const int*)d_in[1];
    const float* w   = (const float*)d_in[2];
    float*       out = (float*)d_out;

    const int M = in_sizes[0] / 64;                   // 262144
    const int blocks = M / (NCHUNK * 64);             // 1024

    cvmm_kernel<<<blocks, 256, 0, stream>>>(x, sel, w, out, M);
}